// Round 1
// baseline (760.768 us; speedup 1.0000x reference)
//
#include <hip/hip_runtime.h>

typedef unsigned short ushort_t;
typedef __attribute__((ext_vector_type(8))) short bf16x8;
typedef __attribute__((ext_vector_type(4))) float f32x4;

// ---------------- problem constants (fixed by setup_inputs) ----------------
#define BB 4
#define HH 512
#define WW 512
#define NPT 2000          // N points kept per image
#define MPT 2500          // M points generated per image
#define CCH 128           // channels
#define FH 128            // feature map h = H/4
#define FW 128
#define FHW (FH*FW)
#define BNP (BB*NPT)      // 8000
#define NPOSC 29
#define NNEGC 80
#define NCOL (1 + NNEGC + BNP)   // 8081 columns in scores/gt
#define PATCH 6                  // candidate offsets span <=6 feature rows/cols

// offsets exactly in the reference enumeration order (j outer, i inner)
__constant__ int c_pos_dy[NPOSC] = {
  0,
  -2,-1,0,1,2,
  -2,-1,0,1,2,
  -3,-2,-1,0,1,2,3,
  -2,-1,0,1,2,
  -2,-1,0,1,2,
  0};
__constant__ int c_pos_dx[NPOSC] = {
  -3,
  -2,-2,-2,-2,-2,
  -1,-1,-1,-1,-1,
  0,0,0,0,0,0,0,
  1,1,1,1,1,
  2,2,2,2,2,
  3};
__constant__ int c_neg_dy[NNEGC] = {
  0,
  -3,-2,-1,0,1,2,3,
  -4,-3,-2,-1,0,1,2,3,4,
  -5,-4,-3,3,4,5,
  -6,-5,-4,4,5,6,
  -6,-5,5,6,
  -6,-5,5,6,
  -7,-6,-5,5,6,7,
  -6,-5,5,6,
  -6,-5,5,6,
  -6,-5,-4,4,5,6,
  -5,-4,-3,3,4,5,
  -4,-3,-2,-1,0,1,2,3,4,
  -3,-2,-1,0,1,2,3,
  0};
__constant__ int c_neg_dx[NNEGC] = {
  -7,
  -6,-6,-6,-6,-6,-6,-6,
  -5,-5,-5,-5,-5,-5,-5,-5,-5,
  -4,-4,-4,-4,-4,-4,
  -3,-3,-3,-3,-3,-3,
  -2,-2,-2,-2,
  -1,-1,-1,-1,
  0,0,0,0,0,0,
  1,1,1,1,
  2,2,2,2,
  3,3,3,3,3,3,
  4,4,4,4,4,4,
  5,5,5,5,5,5,5,5,5,
  6,6,6,6,6,6,6,
  7};

// ---------------- device helpers ----------------
__device__ __forceinline__ ushort_t f2bf(float f) {   // round-to-nearest-even
  unsigned u = __float_as_uint(f);
  unsigned r = (u + 0x7fffu + ((u >> 16) & 1u)) >> 16;
  return (ushort_t)r;
}

// bilinear sample of 2 channels (c = 2*lane, 2*lane+1) from channel-contiguous
// feature map fb[FH][FW][CCH]; fy/fx are feature-scale coords (already /4)
__device__ __forceinline__ float2 sample2(const float* __restrict__ fb,
                                          float fy, float fx, int lane) {
  float y = fminf(fmaxf(fy, 0.f), (float)(FH - 1));
  float x = fminf(fmaxf(fx, 0.f), (float)(FW - 1));
  float y0 = floorf(y), x0 = floorf(x);
  int iy0 = (int)y0, ix0 = (int)x0;
  int iy1 = min(iy0 + 1, FH - 1), ix1 = min(ix0 + 1, FW - 1);
  float wy = y - y0, wx = x - x0;
  float w00 = (1.f - wy) * (1.f - wx), w01 = (1.f - wy) * wx;
  float w10 = wy * (1.f - wx),         w11 = wy * wx;
  int c = 2 * lane;
  float2 a00 = *(const float2*)(fb + ((size_t)iy0 * FW + ix0) * CCH + c);
  float2 a01 = *(const float2*)(fb + ((size_t)iy0 * FW + ix1) * CCH + c);
  float2 a10 = *(const float2*)(fb + ((size_t)iy1 * FW + ix0) * CCH + c);
  float2 a11 = *(const float2*)(fb + ((size_t)iy1 * FW + ix1) * CCH + c);
  float2 r;
  r.x = w00 * a00.x + w01 * a01.x + w10 * a10.x + w11 * a11.x;
  r.y = w00 * a00.y + w01 * a01.y + w10 * a10.y + w11 * a11.y;
  return r;
}

// single-channel bilinear on conf map cb[FH][FW]; py/px are IMAGE-scale coords
__device__ __forceinline__ float conf_sample(const float* __restrict__ cb,
                                             float py, float px) {
  float y = fminf(fmaxf(py * 0.25f, 0.f), (float)(FH - 1));
  float x = fminf(fmaxf(px * 0.25f, 0.f), (float)(FW - 1));
  float y0 = floorf(y), x0 = floorf(x);
  int iy0 = (int)y0, ix0 = (int)x0;
  int iy1 = min(iy0 + 1, FH - 1), ix1 = min(ix0 + 1, FW - 1);
  float wy = y - y0, wx = x - x0;
  return (1.f - wy) * (1.f - wx) * cb[iy0 * FW + ix0]
       + (1.f - wy) * wx         * cb[iy0 * FW + ix1]
       + wy * (1.f - wx)         * cb[iy1 * FW + ix0]
       + wy * wx                 * cb[iy1 * FW + ix1];
}

__device__ __forceinline__ float wave_sum(float v) {
#pragma unroll
  for (int o = 32; o > 0; o >>= 1) v += __shfl_xor(v, o, 64);
  return v;
}

// per-lane partial (dot, ss) of one candidate read from the LDS patch.
// sp = s_patch[PATCH][PATCH][CCH]; lane covers channels sub*8 .. sub*8+7.
__device__ __forceinline__ void cand_partial_lds(const float* __restrict__ sp,
                                                 int py, int px, int r0, int c0,
                                                 int dy, int dx, int sub,
                                                 const float* __restrict__ a8,
                                                 float& dot, float& ss) {
  float cy = fminf(fmaxf((float)(py + dy), 0.f), (float)(HH - 1)) * 0.25f;
  float cx = fminf(fmaxf((float)(px + dx), 0.f), (float)(WW - 1)) * 0.25f;
  float y = fminf(cy, (float)(FH - 1));
  float x = fminf(cx, (float)(FW - 1));
  float y0 = floorf(y), x0 = floorf(x);
  int iy0 = (int)y0, ix0 = (int)x0;
  int iy1 = min(iy0 + 1, FH - 1) - r0, ix1 = min(ix0 + 1, FW - 1) - c0;
  iy0 -= r0; ix0 -= c0;                 // local patch coords, in [0, PATCH)
  float wy = y - y0, wx = x - x0;
  float w00 = (1.f - wy) * (1.f - wx), w01 = (1.f - wy) * wx;
  float w10 = wy * (1.f - wx),         w11 = wy * wx;
  const float* p00 = sp + (iy0 * PATCH + ix0) * CCH + sub * 8;
  const float* p01 = sp + (iy0 * PATCH + ix1) * CCH + sub * 8;
  const float* p10 = sp + (iy1 * PATCH + ix0) * CCH + sub * 8;
  const float* p11 = sp + (iy1 * PATCH + ix1) * CCH + sub * 8;
  float c00[8], c01[8], c10[8], c11[8];
  *(float4*)&c00[0] = *(const float4*)p00; *(float4*)&c00[4] = *(const float4*)(p00 + 4);
  *(float4*)&c01[0] = *(const float4*)p01; *(float4*)&c01[4] = *(const float4*)(p01 + 4);
  *(float4*)&c10[0] = *(const float4*)p10; *(float4*)&c10[4] = *(const float4*)(p10 + 4);
  *(float4*)&c11[0] = *(const float4*)p11; *(float4*)&c11[4] = *(const float4*)(p11 + 4);
  float d = 0.f, s = 0.f;
#pragma unroll
  for (int ch = 0; ch < 8; ++ch) {
    float v = w00 * c00[ch] + w01 * c01[ch] + w10 * c10[ch] + w11 * c11[ch];
    d += a8[ch] * v;
    s += v * v;
  }
  dot = d; ss = s;
}

__device__ __forceinline__ void better(float& best, int& bidx, float ob, int oi) {
  if (ob > best || (ob == best && oi < bidx)) { best = ob; bidx = oi; }
}

// ---------------- K1: transpose feats [C][h][w] -> [h][w][C] ----------------
__global__ __launch_bounds__(256) void k_transpose(const float* __restrict__ feat0,
                                                   const float* __restrict__ feat1,
                                                   float* __restrict__ ft0,
                                                   float* __restrict__ ft1) {
  __shared__ float tile[32][33];
  int z = blockIdx.z;
  const float* src = (z < BB) ? feat0 + (size_t)z * CCH * FHW
                              : feat1 + (size_t)(z - BB) * CCH * FHW;
  float* dst = (z < BB) ? ft0 + (size_t)z * CCH * FHW
                        : ft1 + (size_t)(z - BB) * CCH * FHW;
  int p0 = blockIdx.x * 32;   // position tile (p = y*FW + x)
  int c0 = blockIdx.y * 32;   // channel tile
  int tx = threadIdx.x & 31, ty = threadIdx.x >> 5;  // ty 0..7
#pragma unroll
  for (int jj = 0; jj < 32; jj += 8)
    tile[ty + jj][tx] = src[(size_t)(c0 + ty + jj) * FHW + p0 + tx];
  __syncthreads();
#pragma unroll
  for (int jj = 0; jj < 32; jj += 8)
    dst[(size_t)(p0 + ty + jj) * CCH + c0 + tx] = tile[tx][ty + jj];
}

// ---------------- K2: fused per-point kernel ---------------------------------
// One point per block (256 threads = 4 waves).
//   wave 0: vf0 = l2norm(bilinear(pos0/4, feat0))  -> LDS + vf0_bf
//   wave 1: dist = l2norm(bilinear(pos1[M-N:]/4, feat1)) -> dist_bf
//   wave 2: mask
//   all:    stage the 6x6x128 candidate patch of ft1 into LDS
// then 16-lane-group candidate scoring entirely out of LDS, plus
// gt cols 0..80 writes (zeros + col0=1), qconf.
__global__ __launch_bounds__(256) void k_cand(const float* __restrict__ ft0,
                                              const float* __restrict__ ft1,
                                              const float* __restrict__ conf0,
                                              const float* __restrict__ conf1,
                                              const int* __restrict__ pos0,
                                              const int* __restrict__ pos1,
                                              ushort_t* __restrict__ vf0_bf,
                                              ushort_t* __restrict__ dist_bf,
                                              float* __restrict__ scores,
                                              float* __restrict__ gt,
                                              float* __restrict__ mask_out,
                                              float* __restrict__ qconf_out) {
  __shared__ float s_patch[PATCH * PATCH * CCH];   // 18.4 KB
  __shared__ float s_vf0[CCH];
  __shared__ float s_best[4];
  __shared__ int   s_idx[4];

  int n = blockIdx.x;
  int b = n / NPT, r = n - b * NPT;
  int tid = threadIdx.x;
  int lane = tid & 63, wv = tid >> 6;

  int py = pos1[(b * MPT + r) * 2 + 0];
  int px = pos1[(b * MPT + r) * 2 + 1];
  // patch origin (floor-div by 4 with clamp so patch stays inside [0,127])
  int r0 = min(max((py - 7) >> 2, 0), FH - PATCH);
  int c0 = min(max((px - 7) >> 2, 0), FW - PATCH);
  const float* fb1 = ft1 + (size_t)b * FHW * CCH;

  // ---- per-wave role work (independent; no barrier needed until patch use) --
  if (wv == 0) {
    // vf0 for this point
    const float* fb0 = ft0 + (size_t)b * FHW * CCH;
    float qy = (float)pos0[(b * MPT + r) * 2 + 0];
    float qx = (float)pos0[(b * MPT + r) * 2 + 1];
    float2 v = sample2(fb0, qy * 0.25f, qx * 0.25f, lane);
    float ssum = wave_sum(v.x * v.x + v.y * v.y);
    float inv = 1.f / fmaxf(sqrtf(ssum), 1e-12f);
    v.x *= inv; v.y *= inv;
    s_vf0[2 * lane] = v.x; s_vf0[2 * lane + 1] = v.y;
    ushort2 p; p.x = f2bf(v.x); p.y = f2bf(v.y);
    *(ushort2*)(vf0_bf + (size_t)n * CCH + 2 * lane) = p;
  } else if (wv == 1) {
    // dist row for this point (independent subsample of pos1)
    float qy = (float)pos1[(b * MPT + (MPT - NPT) + r) * 2 + 0];
    float qx = (float)pos1[(b * MPT + (MPT - NPT) + r) * 2 + 1];
    float2 v = sample2(fb1, qy * 0.25f, qx * 0.25f, lane);
    float ssum = wave_sum(v.x * v.x + v.y * v.y);
    float inv = 1.f / fmaxf(sqrtf(ssum), 1e-12f);
    v.x *= inv; v.y *= inv;
    ushort2 p; p.x = f2bf(v.x); p.y = f2bf(v.y);
    *(ushort2*)(dist_bf + (size_t)n * CCH + 2 * lane) = p;
  } else if (wv == 2 && lane == 0) {
    mask_out[n] = (px >= 0 && px < WW && py >= 0 && py < HH) ? 1.f : 0.f;
  }

  // ---- stage patch: 6 rows x (6 cols x 128 ch contiguous) = 1152 float4 ----
  {
    float4* sp4 = (float4*)s_patch;
#pragma unroll
    for (int i4 = tid; i4 < PATCH * PATCH * CCH / 4; i4 += 256) {
      int rr = i4 / (PATCH * CCH / 4);
      int k  = i4 - rr * (PATCH * CCH / 4);
      sp4[i4] = *(const float4*)(fb1 + ((size_t)(r0 + rr) * FW + c0) * CCH + 4 * k);
    }
  }
  __syncthreads();

  int g = lane >> 4;            // candidate slot within wave (0..3)
  int sub = lane & 15;          // channel group; ch = sub*8 .. sub*8+7
  float a8[8];
  *(float4*)&a8[0] = *(const float4*)(s_vf0 + sub * 8);
  *(float4*)&a8[4] = *(const float4*)(s_vf0 + sub * 8 + 4);

  // ---- positive candidates: p = it*16 + wv*4 + g, it = 0..1 (p < 29) ------
  float best = -1e30f; int bidx = 0x7fffffff;
#pragma unroll
  for (int it = 0; it < 2; ++it) {
    int p = it * 16 + wv * 4 + g;
    int pc = min(p, NPOSC - 1);
    float dot, ss;
    cand_partial_lds(s_patch, py, px, r0, c0, c_pos_dy[pc], c_pos_dx[pc],
                     sub, a8, dot, ss);
#pragma unroll
    for (int o = 1; o < 16; o <<= 1) {
      dot += __shfl_xor(dot, o, 64);
      ss  += __shfl_xor(ss,  o, 64);
    }
    float sc = dot / fmaxf(sqrtf(ss), 1e-12f);
    if (p < NPOSC && sc > best) { best = sc; bidx = p; }  // strict > = first max
  }
  // combine the 4 groups of this wave (tie-break: smaller index)
  {
    float ob = __shfl_xor(best, 16, 64); int oi = __shfl_xor(bidx, 16, 64);
    better(best, bidx, ob, oi);
    ob = __shfl_xor(best, 32, 64); oi = __shfl_xor(bidx, 32, 64);
    better(best, bidx, ob, oi);
  }
  if (lane == 0) { s_best[wv] = best; s_idx[wv] = bidx; }
  __syncthreads();
  if (tid == 0) {
    float bb = s_best[0]; int bi = s_idx[0];
#pragma unroll
    for (int w2 = 1; w2 < 4; ++w2) better(bb, bi, s_best[w2], s_idx[w2]);
    scores[(size_t)n * NCOL] = bb;
    gt[(size_t)n * NCOL] = 1.0f;
    float q0 = conf_sample(conf0 + (size_t)b * FHW,
                           (float)pos0[(b * MPT + r) * 2 + 0],
                           (float)pos0[(b * MPT + r) * 2 + 1]);
    float sy = fminf(fmaxf((float)(py + c_pos_dy[bi]), 0.f), (float)(HH - 1));
    float sx = fminf(fmaxf((float)(px + c_pos_dx[bi]), 0.f), (float)(WW - 1));
    float q1 = conf_sample(conf1 + (size_t)b * FHW, sy, sx);
    qconf_out[n] = 0.5f * (q0 + q1);
  }

  // ---- negative candidates: p = it*16 + wv*4 + g, it = 0..4 (exactly 80) --
#pragma unroll
  for (int it = 0; it < 5; ++it) {
    int p = it * 16 + wv * 4 + g;
    float dot, ss;
    cand_partial_lds(s_patch, py, px, r0, c0, c_neg_dy[p], c_neg_dx[p],
                     sub, a8, dot, ss);
#pragma unroll
    for (int o = 1; o < 16; o <<= 1) {
      dot += __shfl_xor(dot, o, 64);
      ss  += __shfl_xor(ss,  o, 64);
    }
    if (sub == 0) {
      scores[(size_t)n * NCOL + 1 + p] = dot / fmaxf(sqrtf(ss), 1e-12f);
      gt[(size_t)n * NCOL + 1 + p] = 0.f;   // gt cols 1..80
    }
  }
}

// ---------------- K3: MFMA GEMM scores[:,81:] = vf0 @ dist.T (masked) -------
// A (vf0_bf) and B (dist_bf) are both [BNP][CCH] bf16, K-contiguous.
// Fragments loaded DIRECTLY from global (4 MB total -> lives in L2).
// Also zero-fills the matching gt tile (gt cols 81..) - replaces k_zero.
__global__ __launch_bounds__(256) void k_gemm(const ushort_t* __restrict__ vf0_bf,
                                              const ushort_t* __restrict__ dist_bf,
                                              const int* __restrict__ pos1,
                                              float* __restrict__ scores,
                                              float* __restrict__ gt) {
  int i0 = blockIdx.x * 128, j0 = blockIdx.y * 128;
  int tid = threadIdx.x, lane = tid & 63, wv = tid >> 6;
  int wm = wv >> 1, wn = wv & 1;            // 2x2 wave grid (64x64 per wave)
  int mrow = lane & 15, quad = lane >> 4;

  __shared__ float s_ry[128], s_rx[128], s_rb[128];
  __shared__ float s_cy[128], s_cx[128], s_cb[128];
  if (tid < 128) {
    int i = min(i0 + tid, BNP - 1);
    int b = i / NPT, rr = i - b * NPT;
    s_ry[tid] = (float)pos1[(b * MPT + rr) * 2 + 0];
    s_rx[tid] = (float)pos1[(b * MPT + rr) * 2 + 1];
    s_rb[tid] = (float)b;
  } else {
    int t2 = tid - 128;
    int j = min(j0 + t2, BNP - 1);
    int b = j / NPT, rr = j - b * NPT;
    s_cy[t2] = (float)pos1[(b * MPT + (MPT - NPT) + rr) * 2 + 0];
    s_cx[t2] = (float)pos1[(b * MPT + (MPT - NPT) + rr) * 2 + 1];
    s_cb[t2] = (float)b;
  }
  __syncthreads();

  f32x4 acc[4][4] = {};
  const ushort_t* abase = vf0_bf  + (size_t)(i0 + wm * 64 + mrow) * CCH + quad * 8;
  const ushort_t* bbase = dist_bf + (size_t)(j0 + wn * 64 + mrow) * CCH + quad * 8;
#pragma unroll
  for (int ks = 0; ks < 4; ++ks) {          // K = 4 steps of 32
    bf16x8 af[4], bf[4];
#pragma unroll
    for (int f = 0; f < 4; ++f) {
      af[f] = *(const bf16x8*)(abase + (size_t)f * 16 * CCH + ks * 32);
      bf[f] = *(const bf16x8*)(bbase + (size_t)f * 16 * CCH + ks * 32);
    }
#pragma unroll
    for (int fm = 0; fm < 4; ++fm)
#pragma unroll
      for (int fn = 0; fn < 4; ++fn)
        acc[fm][fn] = __builtin_amdgcn_mfma_f32_16x16x32_bf16(af[fm], bf[fn],
                                                              acc[fm][fn], 0, 0, 0);
  }

  // epilogue: distance mask + coalesced dword stores (cols 81..), gt zeros
  float cy[4], cx[4], cb[4]; int colg[4];
#pragma unroll
  for (int fn = 0; fn < 4; ++fn) {
    int cl = wn * 64 + fn * 16 + mrow;
    cy[fn] = s_cy[cl]; cx[fn] = s_cx[cl]; cb[fn] = s_cb[cl];
    colg[fn] = j0 + cl;
  }
#pragma unroll
  for (int fm = 0; fm < 4; ++fm) {
#pragma unroll
    for (int reg = 0; reg < 4; ++reg) {
      int rl = wm * 64 + fm * 16 + quad * 4 + reg;
      int row = i0 + rl;
      if (row >= BNP) continue;
      float ry = s_ry[rl], rx = s_rx[rl], rb = s_rb[rl];
      size_t base = (size_t)row * NCOL + 1 + NNEGC;
#pragma unroll
      for (int fn = 0; fn < 4; ++fn) {
        if (colg[fn] >= BNP) continue;
        float dy = cy[fn] - ry, dx = cx[fn] - rx;
        float d2 = dy * dy + dx * dx + ((cb[fn] != rb) ? 25.f : 0.f);
        scores[base + colg[fn]] = (d2 < 25.f) ? 0.f : acc[fm][fn][reg];
        gt[base + colg[fn]] = 0.f;
      }
    }
  }
}

// ---------------- launch ----------------
extern "C" void kernel_launch(void* const* d_in, const int* in_sizes, int n_in,
                              void* d_out, int out_size, void* d_ws, size_t ws_size,
                              hipStream_t stream) {
  (void)in_sizes; (void)n_in; (void)out_size; (void)ws_size;
  const float* feat0 = (const float*)d_in[0];
  const float* feat1 = (const float*)d_in[1];
  const float* conf0 = (const float*)d_in[2];
  const float* conf1 = (const float*)d_in[3];
  const int*   pos0  = (const int*)d_in[4];
  const int*   pos1  = (const int*)d_in[5];

  float* ws = (float*)d_ws;
  float* ft0 = ws;                                      // 4*128*128*128 f32
  float* ft1 = ft0 + (size_t)BB * CCH * FHW;
  ushort_t* vf0_bf  = (ushort_t*)(ft1 + (size_t)BB * CCH * FHW);  // 8000*128 bf16
  ushort_t* dist_bf = vf0_bf + (size_t)BNP * CCH;                 // 8000*128 bf16

  float* out    = (float*)d_out;
  float* scores = out;                                  // [8000][8081]
  float* gt     = out + (size_t)BNP * NCOL;             // [8000][8081]
  float* maskp  = gt + (size_t)BNP * NCOL;              // [8000]
  float* qconf  = maskp + BNP;                          // [8000]

  dim3 g1(FHW / 32, CCH / 32, 2 * BB);
  k_transpose<<<g1, dim3(256), 0, stream>>>(feat0, feat1, ft0, ft1);
  k_cand<<<dim3(BNP), dim3(256), 0, stream>>>(ft0, ft1, conf0, conf1, pos0, pos1,
                                              vf0_bf, dist_bf, scores, gt,
                                              maskp, qconf);
  dim3 g3((BNP + 127) / 128, (BNP + 127) / 128);
  k_gemm<<<g3, dim3(256), 0, stream>>>(vf0_bf, dist_bf, pos1, scores, gt);
}